// Round 7
// baseline (309.000 us; speedup 1.0000x reference)
//
#include <hip/hip_runtime.h>
#include <math.h>

// MADE autoregressive sampler, incremental-by-degree, v17.
// B=8192, D=64, CTX=256, H=512. Units sorted by degree (mh = h%63+1).
// v17: producer-consumer wave specialization. Evidence across v14/v15/v16:
// duration pinned 180-185us regardless of occupancy (12 vs 32 waves/CU) or
// weight amortization (Rn 8 vs 16); VALUBusy <= 45%; FLOP floor ~26us.
// => per-step serial chain (3 block-wide barriers + exposed LDS/L2 latency,
// with all 512-unit threads riding every chain phase) is the limiter.
// Fix: block = 4 bulk waves (256 thr, v16 unit/oc layout) + 1 critical wave.
//  - crit wave, step sc: D-final col sc (och handoff + Wo[col sc]*h2_{sc-1})
//    -> softplus/sample z_sc -> FA-final group sc (a1h + W1*z_{sc-1} + W1*z_sc)
//    -> in-group MID (a2h + W2*h1_{sc-1} + W2*h1_sc) -> publish z/h1/h2.
//    All cross-lane via LDS + wave-internal lgkmcnt (NO barriers).
//  - bulk waves, step sc-1: straight-line FA+MID+D for all units/cols (no
//    internal syncs), consuming crit's step-(sc-1) publishes; then hand off
//    group-(sc+1) a1/a2 and col-(sc+1) oc state.
//  - ONE barrier per step (was 3). All pub/handoff buffers double-buffered
//    by step parity (audited: reader parity != writer parity same interval).
// Handoff lag algebra: handoff written interval S reflects inputs through
// step S-1 => crit adds exactly one recent term + current term per state.
// 8-wide groups (sc>=8): j=8 lane guarded; stale h1pub[8]/h2pub[8] are
// multiplied by prep-zeroed slot-8 weights => harmless (same trick as v16).
// Prep unchanged.

typedef float f2 __attribute__((ext_vector_type(2)));

#define Bn 8192
#define Dn 64
#define CTXn 256
#define Hn 512
#define Rn 16
#define BD (Bn * Dn)

#define WQ_SZ  (64 * 512 * 12)   // 393216
#define WOQ_SZ (64 * 64 * 20)    //  81920
#define WCP_SZ (CTXn * Hn)       // 131072

// lgkm-only block barrier: drains LDS ops, leaves global loads in flight.
#define BARRIER() do {                                      \
    asm volatile("s_waitcnt lgkmcnt(0)" ::: "memory");      \
    __builtin_amdgcn_s_barrier();                           \
    asm volatile("" ::: "memory");                          \
  } while (0)

// wave-internal LDS fence (no barrier): lgkm drain + compiler memory fence.
#define WAVE_LDS_FENCE() do {                               \
    asm volatile("s_waitcnt lgkmcnt(0)" ::: "memory");      \
  } while (0)

// sorted index p -> original hidden unit h, and its degree k.
__device__ __forceinline__ int perm_of(int p, int* degout) {
  int k, t;
  if (p < 72) { k = p / 9 + 1; t = p - (k - 1) * 9; }
  else        { int pp = p - 72; k = pp / 8 + 9; t = pp - (k - 9) * 8; }
  *degout = k;
  return (k - 1) + 63 * t;
}
// original unit h -> sorted index q.
__device__ __forceinline__ int inv_perm(int h) {
  int i = h % 63;            // = degree-1
  int t = h / 63;
  int base = (i < 9) ? 9 * i : 72 + 8 * (i - 8);   // S_of(i+1)
  return base + t;
}

// ---------------- prep: scan-order, coalesced reads (unchanged) -------------
#define R0e 262144
#define R1e (R0e + 32768)
#define R2e (R1e + 65536)
#define R3e (R2e + 131072)
#define R4e (R3e + 35840)
#define R5e (R4e + 1024)
__global__ void prep_kernel(const float* __restrict__ W1, const float* __restrict__ Wc,
                            const float* __restrict__ W2, const float* __restrict__ Wo,
                            const float* __restrict__ b1, const float* __restrict__ b2,
                            float* __restrict__ Wq, float* __restrict__ Woq,
                            float* __restrict__ WcpT, float* __restrict__ b1p,
                            float* __restrict__ b2p) {
  int idx = blockIdx.x * 256 + threadIdx.x;
  if (idx < R0e) {                      // W2 scan (coalesced read)
    int hq = idx >> 9, hp = idx & 511;
    int i = hp % 63, e = hp / 63;
    Wq[i * 6144 + inv_perm(hq) * 12 + e] = W2[idx];
  } else if (idx < R1e) {               // W1 scan
    int jj = idx - R0e;
    int hq = jj >> 6, i = jj & 63;
    Wq[i * 6144 + inv_perm(hq) * 12 + 9] = W1[jj];
  } else if (idx < R2e) {               // Wo scan
    int jj = idx - R1e;
    int o = jj >> 9, hp = jj & 511;
    int i = hp % 63, p = hp / 63;
    int j = o & 63, half = o >> 6;
    Woq[i * 1280 + j * 20 + half * 10 + p] = Wo[jj];
  } else if (idx < R3e) {               // Wc scan (pair-interleaved layout)
    int jj = idx - R2e;
    int hq = jj >> 8, cc = jj & 255;
    int p = inv_perm(hq);
    int slot = (p < 256) ? (2 * p) : (2 * (p - 256) + 1);
    WcpT[cc * 512 + slot] = Wc[jj];
  } else if (idx < R4e) {               // zero the 9th slots for 8-wide groups
    int z = idx - R3e;
    if (z < 28672) {                    // Wq[i][q][8], i = 8..63
      int i = 8 + (z >> 9), q = z & 511;
      Wq[i * 6144 + q * 12 + 8] = 0.f;
    } else {                            // Woq[i][j][8 or 18], i = 8..63
      int z2 = z - 28672;
      int i = 8 + (z2 >> 7), r = z2 & 127;
      int j = r & 63, half = r >> 6;
      Woq[i * 1280 + j * 20 + half * 10 + 8] = 0.f;
    }
  } else if (idx < R5e) {               // permuted biases
    int z = idx - R4e;
    if (z < 512) {
      int dq; int hq = perm_of(z, &dq);
      b1p[z] = b1[hq];
    } else {
      int q = z - 512;
      int dq; int hq = perm_of(q, &dq);
      b2p[q] = b2[hq];
    }
  }
}

// ---------------- main fused kernel ------------------------------------------
// 320 threads = 5 waves. t<256: bulk (v16 layout: thread (rp=t>>6, l=t&63)
// owns units q0=t, q1=t+256; oc cols (l,l+64) rows 4rp..4rp+3).
// t>=256: critical wave, lane l=t&63 -> (j = l>>4, r = l&15) handles group
// values (j,r), (j+4,r), and (8,r) for l<16 when the group has 9 units.
__global__ __launch_bounds__(320, 2)
void made_pk_kernel(
    const float* __restrict__ context, const float* __restrict__ WcpT,
    const float* __restrict__ b1p,
    const float* __restrict__ Wq, const float* __restrict__ Woq,
    const float* __restrict__ b2p, const float* __restrict__ bo,
    const float* __restrict__ eps, float* __restrict__ out) {
  __shared__ __align__(16) float ctxR[Rn][264];
  __shared__ __align__(16) float zpub[2][16];     // z_i (crit -> bulk/crit)
  __shared__ __align__(16) float h1pub[2][9][16]; // h1 group i
  __shared__ __align__(16) float h2pub[2][9][16]; // h2 group i
  __shared__ __align__(16) float a1h[2][9][16];   // handoff a1, group i+1
  __shared__ __align__(16) float a2h[2][9][16];   // handoff a2, group i+1
  __shared__ __align__(16) float och[2][32];      // handoff oc, col i+1 (A|B)

  int t = threadIdx.x;
  int b0 = blockIdx.x * Rn;

  if (t < 256) {
    // ======================= BULK WAVES =======================
    int rp = t >> 6, l = t & 63;
    int q0 = t, q1 = t + 256;
    int g0 = ((q0 < 72) ? q0 / 9 + 1 : (q0 - 72) / 8 + 9) - 1;
    int g1 = ((q1 - 72) / 8 + 9) - 1;
    int qm = t | 63;
    int gm0s = __builtin_amdgcn_readfirstlane(
        ((qm < 72) ? qm / 9 + 1 : (qm - 72) / 8 + 9) - 1);
    int gm1s = __builtin_amdgcn_readfirstlane(((qm + 256 - 72) / 8 + 9) - 1);

    // ---- stage ctx ----
    #pragma unroll
    for (int r = 0; r < Rn; ++r)
      ctxR[r][t] = context[(b0 + r) * CTXn + t];
    BARRIER();                                   // B1

    // ---- ctx GEMM (v16) ----
    f2 accu[16];
    {
      f2 bias = (f2){b1p[q0], b1p[q1]};
      #pragma unroll
      for (int r = 0; r < 16; ++r) accu[r] = bias;
    }
    {
      const float* wc = WcpT + 2 * t;
      #pragma clang loop unroll(disable)
      for (int c4 = 0; c4 < CTXn / 4; ++c4) {
        f2 wv0 = *(const f2*)&wc[0];
        f2 wv1 = *(const f2*)&wc[Hn];
        f2 wv2 = *(const f2*)&wc[2 * Hn];
        f2 wv3 = *(const f2*)&wc[3 * Hn];
        wc += 4 * Hn;
        #pragma unroll
        for (int hf = 0; hf < 2; ++hf) {
          float4 x[8];
          #pragma unroll
          for (int r = 0; r < 8; ++r) x[r] = *(const float4*)&ctxR[8 * hf + r][4 * c4];
          #pragma unroll
          for (int r = 0; r < 8; ++r) {
            accu[8 * hf + r] += (f2){x[r].x, x[r].x} * wv0;
            accu[8 * hf + r] += (f2){x[r].y, x[r].y} * wv1;
            accu[8 * hf + r] += (f2){x[r].z, x[r].z} * wv2;
            accu[8 * hf + r] += (f2){x[r].w, x[r].w} * wv3;
          }
        }
      }
    }
    f2 a10[8], a11[8], a20[8], a21[8];
    #pragma unroll
    for (int r2 = 0; r2 < 8; ++r2) {
      a10[r2] = (f2){accu[2 * r2].x, accu[2 * r2 + 1].x};
      a11[r2] = (f2){accu[2 * r2].y, accu[2 * r2 + 1].y};
    }
    {
      float bb0 = b2p[q0], bb1 = b2p[q1];
      #pragma unroll
      for (int r2 = 0; r2 < 8; ++r2) {
        a20[r2] = (f2){bb0, bb0};
        a21[r2] = (f2){bb1, bb1};
      }
    }
    f2 ocA[2], ocB[2];
    ocA[0] = ocA[1] = (f2){bo[l], bo[l]};
    ocB[0] = ocB[1] = (f2){bo[l + 64], bo[l + 64]};

    // ---- prologue handoffs: group 0 (parity 1) + col 0 (parity 1) ----
    if (g0 == 0) {                               // threads t = 0..8
      int pp = q0;                               // sb(0) = 0
      #pragma unroll
      for (int s = 0; s < 4; ++s) {
        *(float4*)&a1h[1][pp][4 * s] =
            (float4){a10[2 * s].x, a10[2 * s].y, a10[2 * s + 1].x, a10[2 * s + 1].y};
        *(float4*)&a2h[1][pp][4 * s] =
            (float4){a20[2 * s].x, a20[2 * s].y, a20[2 * s + 1].x, a20[2 * s + 1].y};
      }
    }
    if (l == 0) {                                // col 0 state = bo
      *(float4*)&och[1][4 * rp] =
          (float4){ocA[0].x, ocA[0].y, ocA[1].x, ocA[1].y};
      *(float4*)&och[1][16 + 4 * rp] =
          (float4){ocB[0].x, ocB[0].y, ocB[1].x, ocB[1].y};
    }
    BARRIER();                                   // B2

    // ---- interval loop: one barrier per step ----
    #pragma clang loop unroll(disable)
    for (int S = 0; S < Dn; ++S) {
      if (S >= 1) {
        int i = S - 1;
        int pb = i & 1;
        int sbp = (i < 8) ? 9 * i : 8 * i + 8;   // (unused, kept for clarity)
        (void)sbp;
        bool liveB = (i <= gm1s);
        bool liveA = (i <= gm0s);
        const float* wq0p = Wq + (size_t)i * 6144 + (size_t)q0 * 12;
        const float* wq1p = Wq + (size_t)i * 6144 + (size_t)q1 * 12;
        const float* wopp = Woq + (size_t)i * 1280 + (size_t)l * 20;
        // Wo load early (independent; latency hidden behind FA/MID)
        const float4* w4 = (const float4*)wopp;
        float4 B0 = w4[0], B1 = w4[1], B2_ = w4[2], B3 = w4[3], B4 = w4[4];

        if (liveB) {
          const float4* a4 = (const float4*)wq1p;
          float4 A1c0 = a4[0], A1c1 = a4[1], A1c2 = a4[2];
          float4 A0c0, A0c1, A0c2;
          if (liveA) {
            const float4* b4 = (const float4*)wq0p;
            A0c0 = b4[0]; A0c1 = b4[1]; A0c2 = b4[2];
          }
          float4 za = *(const float4*)&zpub[pb][0];
          float4 zb = *(const float4*)&zpub[pb][4];
          float4 zc = *(const float4*)&zpub[pb][8];
          float4 zd = *(const float4*)&zpub[pb][12];
          f2 zz[8] = {(f2){za.x, za.y}, (f2){za.z, za.w},
                      (f2){zb.x, zb.y}, (f2){zb.z, zb.w},
                      (f2){zc.x, zc.y}, (f2){zc.z, zc.w},
                      (f2){zd.x, zd.y}, (f2){zd.z, zd.w}};
          // FA
          {
            f2 wv = (f2){A1c2.y, A1c2.y};
            #pragma unroll
            for (int r2 = 0; r2 < 8; ++r2) a11[r2] += wv * zz[r2];
          }
          if (liveA) {
            f2 wv = (f2){A0c2.y, A0c2.y};
            #pragma unroll
            for (int r2 = 0; r2 < 8; ++r2) a10[r2] += wv * zz[r2];
          }
          // MID
          float wA1[9] = {A1c0.x, A1c0.y, A1c0.z, A1c0.w,
                          A1c1.x, A1c1.y, A1c1.z, A1c1.w, A1c2.x};
          if (liveA) {
            float wA0[9] = {A0c0.x, A0c0.y, A0c0.z, A0c0.w,
                            A0c1.x, A0c1.y, A0c1.z, A0c1.w, A0c2.x};
            #pragma unroll
            for (int p = 0; p < 9; ++p) {
              float4 ha = *(const float4*)&h1pub[pb][p][0];
              float4 hb = *(const float4*)&h1pub[pb][p][4];
              float4 hc = *(const float4*)&h1pub[pb][p][8];
              float4 hd = *(const float4*)&h1pub[pb][p][12];
              f2 h[8] = {(f2){ha.x, ha.y}, (f2){ha.z, ha.w},
                         (f2){hb.x, hb.y}, (f2){hb.z, hb.w},
                         (f2){hc.x, hc.y}, (f2){hc.z, hc.w},
                         (f2){hd.x, hd.y}, (f2){hd.z, hd.w}};
              f2 wv1 = (f2){wA1[p], wA1[p]};
              f2 wv0 = (f2){wA0[p], wA0[p]};
              #pragma unroll
              for (int r2 = 0; r2 < 8; ++r2) {
                a21[r2] += wv1 * h[r2];
                a20[r2] += wv0 * h[r2];
              }
            }
          } else {
            #pragma unroll
            for (int p = 0; p < 9; ++p) {
              float4 ha = *(const float4*)&h1pub[pb][p][0];
              float4 hb = *(const float4*)&h1pub[pb][p][4];
              float4 hc = *(const float4*)&h1pub[pb][p][8];
              float4 hd = *(const float4*)&h1pub[pb][p][12];
              f2 h[8] = {(f2){ha.x, ha.y}, (f2){ha.z, ha.w},
                         (f2){hb.x, hb.y}, (f2){hb.z, hb.w},
                         (f2){hc.x, hc.y}, (f2){hc.z, hc.w},
                         (f2){hd.x, hd.y}, (f2){hd.z, hd.w}};
              f2 wv1 = (f2){wA1[p], wA1[p]};
              #pragma unroll
              for (int r2 = 0; r2 < 8; ++r2) a21[r2] += wv1 * h[r2];
            }
          }
        }
        // D: oc += Wo[step i] . h2_i  (all cols; already-emitted cols harmless)
        {
          float wBa[9] = {B0.x, B0.y, B0.z, B0.w, B1.x, B1.y, B1.z, B1.w, B2_.x};
          float wBb[9] = {B2_.z, B2_.w, B3.x, B3.y, B3.z, B3.w, B4.x, B4.y, B4.z};
          #pragma unroll
          for (int p = 0; p < 9; ++p) {
            float4 hq = *(const float4*)&h2pub[pb][p][4 * rp];
            f2 h01 = (f2){hq.x, hq.y}, h23 = (f2){hq.z, hq.w};
            f2 wa = (f2){wBa[p], wBa[p]}, wb = (f2){wBb[p], wBb[p]};
            ocA[0] += wa * h01; ocA[1] += wa * h23;
            ocB[0] += wb * h01; ocB[1] += wb * h23;
          }
        }
      }

      // ---- handoffs for crit step S+1 (post-update state; every S) ----
      int ph = S & 1;
      if (S + 1 <= 62) {
        int sb1 = (S + 1 < 8) ? 9 * (S + 1) : 8 * (S + 1) + 8;
        if (g1 == S + 1) {
          int pp = q1 - sb1;
          #pragma unroll
          for (int s = 0; s < 4; ++s) {
            *(float4*)&a1h[ph][pp][4 * s] =
                (float4){a11[2 * s].x, a11[2 * s].y, a11[2 * s + 1].x, a11[2 * s + 1].y};
            *(float4*)&a2h[ph][pp][4 * s] =
                (float4){a21[2 * s].x, a21[2 * s].y, a21[2 * s + 1].x, a21[2 * s + 1].y};
          }
        }
        if (g0 == S + 1) {
          int pp = q0 - sb1;
          #pragma unroll
          for (int s = 0; s < 4; ++s) {
            *(float4*)&a1h[ph][pp][4 * s] =
                (float4){a10[2 * s].x, a10[2 * s].y, a10[2 * s + 1].x, a10[2 * s + 1].y};
            *(float4*)&a2h[ph][pp][4 * s] =
                (float4){a20[2 * s].x, a20[2 * s].y, a20[2 * s + 1].x, a20[2 * s + 1].y};
          }
        }
      }
      if (S + 1 <= 63 && l == S + 1) {
        *(float4*)&och[ph][4 * rp] =
            (float4){ocA[0].x, ocA[0].y, ocA[1].x, ocA[1].y};
        *(float4*)&och[ph][16 + 4 * rp] =
            (float4){ocB[0].x, ocB[0].y, ocB[1].x, ocB[1].y};
      }
      BARRIER();                                 // per-interval barrier
    }
    // bulk writes no outputs (crit streams them)
  } else {
    // ======================= CRITICAL WAVE =======================
    int l = t & 63;                              // lane 0..63
    int r = l & 15;
    int jA = l >> 4;                             // 0..3
    bool lo16 = (l < 16);

    BARRIER();                                   // B1 (match bulk)
    BARRIER();                                   // B2 (match bulk)

    #pragma clang loop unroll(disable)
    for (int sc = 0; sc < Dn; ++sc) {
      int p = sc & 1, pn = p ^ 1;
      int sb = (sc < 8) ? 9 * sc : 8 * sc + 8;
      bool has9 = (sc < 8);
      bool fin = (sc <= 62);                     // group sc exists

      // ---- issue all weight/eps loads first (independent of this interval) --
      float4 Ca0 = {}, Ca1 = {}, Ca2 = {}, Cb0 = {}, Cb1 = {}, Cb2 = {};
      float4 Pa0 = {}, Pa1 = {}, Pa2 = {}, Pb0 = {}, Pb1 = {}, Pb2 = {};
      float4 Cc0 = {}, Cc1 = {}, Cc2 = {}, Pc0 = {}, Pc1 = {}, Pc2 = {};
      if (fin) {
        int qA = sb + jA, qB = qA + 4;
        const float4* ca = (const float4*)(Wq + (size_t)sc * 6144 + (size_t)qA * 12);
        Ca0 = ca[0]; Ca1 = ca[1]; Ca2 = ca[2];
        const float4* cb = (const float4*)(Wq + (size_t)sc * 6144 + (size_t)qB * 12);
        Cb0 = cb[0]; Cb1 = cb[1]; Cb2 = cb[2];
        if (sc >= 1) {
          const float4* pa = (const float4*)(Wq + (size_t)(sc - 1) * 6144 + (size_t)qA * 12);
          Pa0 = pa[0]; Pa1 = pa[1]; Pa2 = pa[2];
          const float4* pb_ = (const float4*)(Wq + (size_t)(sc - 1) * 6144 + (size_t)qB * 12);
          Pb0 = pb_[0]; Pb1 = pb_[1]; Pb2 = pb_[2];
        }
        if (has9 && lo16) {
          int qC = sb + 8;
          const float4* cc = (const float4*)(Wq + (size_t)sc * 6144 + (size_t)qC * 12);
          Cc0 = cc[0]; Cc1 = cc[1]; Cc2 = cc[2];
          if (sc >= 1) {
            const float4* pc = (const float4*)(Wq + (size_t)(sc - 1) * 6144 + (size_t)qC * 12);
            Pc0 = pc[0]; Pc1 = pc[1]; Pc2 = pc[2];
          }
        }
      }
      float woA[9], woB[9];
      float epsv = 0.f;
      if (lo16) {
        epsv = eps[(b0 + r) * Dn + sc];
        if (sc >= 1) {
          const float4* wo = (const float4*)(Woq + (size_t)(sc - 1) * 1280 + (size_t)sc * 20);
          float4 W0 = wo[0], W1_ = wo[1], W2v = wo[2], W3 = wo[3], W4 = wo[4];
          woA[0] = W0.x; woA[1] = W0.y; woA[2] = W0.z; woA[3] = W0.w;
          woA[4] = W1_.x; woA[5] = W1_.y; woA[6] = W1_.z; woA[7] = W1_.w;
          woA[8] = W2v.x;
          woB[0] = W2v.z; woB[1] = W2v.w; woB[2] = W3.x; woB[3] = W3.y;
          woB[4] = W3.z; woB[5] = W3.w; woB[6] = W4.x; woB[7] = W4.y;
          woB[8] = W4.z;
        }
      }

      // ---- D-final + E (lanes 0..15): col sc for all 16 rows ----
      if (lo16) {
        float ocAv = och[pn][r];
        float ocBv = och[pn][16 + r];
        if (sc >= 1) {
          #pragma unroll
          for (int k = 0; k < 9; ++k) {
            float h2v = h2pub[pn][k][r];
            ocAv = fmaf(woA[k], h2v, ocAv);
            ocBv = fmaf(woB[k], h2v, ocBv);
          }
        }
        float sp = fmaxf(ocBv, 0.f) + __logf(1.f + __expf(-fabsf(ocBv)));
        float z = ocAv + sp * epsv;
        zpub[p][r] = z;
        out[(b0 + r) * Dn + sc] = z;
        out[BD + (b0 + r) * Dn + sc] = ocAv;
        out[2 * BD + (b0 + r) * Dn + sc] = sp;
      }
      WAVE_LDS_FENCE();                          // z visible wave-internally

      if (fin) {
        float zc = zpub[p][r];
        float zp = (sc >= 1) ? zpub[pn][r] : 0.f;
        // FA-final: h1 = relu(a1h + W1[sc-1]*z_{sc-1} + W1[sc]*z_sc)
        {
          float a1A = a1h[pn][jA][r] + Ca2.y * zc + Pa2.y * zp;
          h1pub[p][jA][r] = fmaxf(a1A, 0.f);
          float a1B = a1h[pn][jA + 4][r] + Cb2.y * zc + Pb2.y * zp;
          h1pub[p][jA + 4][r] = fmaxf(a1B, 0.f);
          if (has9 && lo16) {
            float a1C = a1h[pn][8][r] + Cc2.y * zc + Pc2.y * zp;
            h1pub[p][8][r] = fmaxf(a1C, 0.f);
          }
        }
        WAVE_LDS_FENCE();                        // h1 visible wave-internally
        // MID-final: h2 = relu(a2h + W2[sc-1]*h1_{sc-1} + W2[sc]*h1_sc)
        {
          float hc[9], hp[9];
          #pragma unroll
          for (int k = 0; k < 9; ++k) hc[k] = h1pub[p][k][r];
          if (sc >= 1) {
            #pragma unroll
            for (int k = 0; k < 9; ++k) hp[k] = h1pub[pn][k][r];
          } else {
            #pragma unroll
            for (int k = 0; k < 9; ++k) hp[k] = 0.f;
          }
          float wcA[9] = {Ca0.x, Ca0.y, Ca0.z, Ca0.w,
                          Ca1.x, Ca1.y, Ca1.z, Ca1.w, Ca2.x};
          float wpA[9] = {Pa0.x, Pa0.y, Pa0.z, Pa0.w,
                          Pa1.x, Pa1.y, Pa1.z, Pa1.w, Pa2.x};
          float a2A = a2h[pn][jA][r];
          #pragma unroll
          for (int k = 0; k < 9; ++k) a2A = fmaf(wcA[k], hc[k], a2A);
          #pragma unroll
          for (int k = 0; k < 9; ++k) a2A = fmaf(wpA[k], hp[k], a2A);
          h2pub[p][jA][r] = fmaxf(a2A, 0.f);

          float wcB[9] = {Cb0.x, Cb0.y, Cb0.z, Cb0.w,
                          Cb1.x, Cb1.y, Cb1.z, Cb1.w, Cb2.x};
          float wpB[9] = {Pb0.x, Pb0.y, Pb0.z, Pb0.w,
                          Pb1.x, Pb1.y, Pb1.z, Pb1.w, Pb2.x};
          float a2B = a2h[pn][jA + 4][r];
          #pragma unroll
          for (int k = 0; k < 9; ++k) a2B = fmaf(wcB[k], hc[k], a2B);
          #pragma unroll
          for (int k = 0; k < 9; ++k) a2B = fmaf(wpB[k], hp[k], a2B);
          h2pub[p][jA + 4][r] = fmaxf(a2B, 0.f);

          if (has9 && lo16) {
            float wcC[9] = {Cc0.x, Cc0.y, Cc0.z, Cc0.w,
                            Cc1.x, Cc1.y, Cc1.z, Cc1.w, Cc2.x};
            float wpC[9] = {Pc0.x, Pc0.y, Pc0.z, Pc0.w,
                            Pc1.x, Pc1.y, Pc1.z, Pc1.w, Pc2.x};
            float a2C = a2h[pn][8][r];
            #pragma unroll
            for (int k = 0; k < 9; ++k) a2C = fmaf(wcC[k], hc[k], a2C);
            #pragma unroll
            for (int k = 0; k < 9; ++k) a2C = fmaf(wpC[k], hp[k], a2C);
            h2pub[p][8][r] = fmaxf(a2C, 0.f);
          }
        }
      }
      BARRIER();                                 // per-interval barrier
    }
  }
}

extern "C" void kernel_launch(void* const* d_in, const int* in_sizes, int n_in,
                              void* d_out, int out_size, void* d_ws, size_t ws_size,
                              hipStream_t stream) {
  const float* context = (const float*)d_in[0];
  const float* eps     = (const float*)d_in[1];
  const float* W1      = (const float*)d_in[2];
  const float* b1      = (const float*)d_in[3];
  const float* Wc      = (const float*)d_in[4];
  const float* W2      = (const float*)d_in[5];
  const float* b2      = (const float*)d_in[6];
  const float* Wo      = (const float*)d_in[7];
  const float* bo      = (const float*)d_in[8];
  float* out = (float*)d_out;

  float* ws   = (float*)d_ws;
  float* Wq   = ws;                        // 393216 floats
  float* Woq  = Wq + WQ_SZ;                //  81920
  float* WcpT = Woq + WOQ_SZ;              // 131072
  float* b1p  = WcpT + WCP_SZ;             //    512
  float* b2p  = b1p + 512;                 //    512
  // total ws use: ~2.4 MB (L2-resident)

  prep_kernel<<<(R5e + 255) / 256, 256, 0, stream>>>(
      W1, Wc, W2, Wo, b1, b2, Wq, Woq, WcpT, b1p, b2p);
  made_pk_kernel<<<Bn / Rn, 320, 0, stream>>>(context, WcpT, b1p, Wq, Woq,
                                              b2p, bo, eps, out);
}

// Round 8
// 264.807 us; speedup vs baseline: 1.1669x; 1.1669x over previous
//
#include <hip/hip_runtime.h>
#include <math.h>

// MADE autoregressive sampler, incremental-by-degree, v18.
// B=8192, D=64, CTX=256, H=512. Units sorted by degree (mh = h%63+1).
// v18: two-barrier lag schedule. v15/v16/v17 jointly show: total VALU issue
// ~72us-equiv is structure-invariant; the ~110us of stall is the 3-barrier
// phase structure (each phase exposes an LDS round-trip or weight load on the
// block critical path). v17's producer/consumer failed (250us) because the
// per-step barrier still locks the waves together and handoffs added work.
// Fix, keeping v16's layout (256 thr, q0=t,q1=t+256, Rn=16):
//  phase 1 (bulk, lagged one step): D-accum(h2_{S-1}) -> E_S (softplus, z_S,
//    thread-local oc complete since its own D-accum precedes) -> FA-accum
//    (z_{S-1}) + MID-accum(h1_{S-1}) in ONE fused pass.  BARRIER.
//  phase 2 (finals, inline): group-S owner threads add the single missing
//    terms in their OWN registers: FA-final a1 += W1[S]*z_S -> publish h1_S;
//    wave-internal fence (group units are wave-contiguous; the ONE exception
//    is group 7, threads 63..71 -> extra BARRIER at S==7 only); MID-final
//    a2 += W2[S]*h1_S (in-group 9x) -> publish h2_S.  BARRIER.
// 2 barriers/step (was 3), no handoffs (finalizing thread IS the accumulator),
// bulk is one straight-line pass. Wq[S] prefetched in phase 1 (register
// rotation) -> feeds phase-2 finals AND next step's bulk with latency hidden;
// VGPR cap is 256 now (launch_bounds(256,2)) vs v13's 64-cap spill disaster.
// Spill tripwire: WRITE_SIZE must stay 6144 KB.
// Lag algebra: at phase 2 of step g, a1 = ctx + sum z_0..z_{g-1} (bulk step i
// adds z_{i-1}); a2 = b2 + sum h1_0..h1_{g-1}; oc = bo + sum h2_0..h2_{g-1}.
// Stale slot-8 lanes killed by prep-zeroed weights (v16 trick). Parity:
// phase-2 writes [S&1]; bulk step S+1 reads [S&1]; next write to that parity
// is phase 2 of S+2, two barriers later.

typedef float f2 __attribute__((ext_vector_type(2)));

#define Bn 8192
#define Dn 64
#define CTXn 256
#define Hn 512
#define Rn 16
#define BD (Bn * Dn)

#define WQ_SZ  (64 * 512 * 12)   // 393216
#define WOQ_SZ (64 * 64 * 20)    //  81920
#define WCP_SZ (CTXn * Hn)       // 131072

// lgkm-only block barrier: drains LDS ops, leaves global loads in flight.
#define BARRIER() do {                                      \
    asm volatile("s_waitcnt lgkmcnt(0)" ::: "memory");      \
    __builtin_amdgcn_s_barrier();                           \
    asm volatile("" ::: "memory");                          \
  } while (0)

// wave-internal LDS fence (no barrier).
#define WAVE_LDS_FENCE() do {                               \
    asm volatile("s_waitcnt lgkmcnt(0)" ::: "memory");      \
  } while (0)

// sorted index p -> original hidden unit h, and its degree k.
__device__ __forceinline__ int perm_of(int p, int* degout) {
  int k, t;
  if (p < 72) { k = p / 9 + 1; t = p - (k - 1) * 9; }
  else        { int pp = p - 72; k = pp / 8 + 9; t = pp - (k - 9) * 8; }
  *degout = k;
  return (k - 1) + 63 * t;
}
// original unit h -> sorted index q.
__device__ __forceinline__ int inv_perm(int h) {
  int i = h % 63;            // = degree-1
  int t = h / 63;
  int base = (i < 9) ? 9 * i : 72 + 8 * (i - 8);   // S_of(i+1)
  return base + t;
}

// ---------------- prep: scan-order, coalesced reads (unchanged) -------------
#define R0e 262144
#define R1e (R0e + 32768)
#define R2e (R1e + 65536)
#define R3e (R2e + 131072)
#define R4e (R3e + 35840)
#define R5e (R4e + 1024)
__global__ void prep_kernel(const float* __restrict__ W1, const float* __restrict__ Wc,
                            const float* __restrict__ W2, const float* __restrict__ Wo,
                            const float* __restrict__ b1, const float* __restrict__ b2,
                            float* __restrict__ Wq, float* __restrict__ Woq,
                            float* __restrict__ WcpT, float* __restrict__ b1p,
                            float* __restrict__ b2p) {
  int idx = blockIdx.x * 256 + threadIdx.x;
  if (idx < R0e) {                      // W2 scan (coalesced read)
    int hq = idx >> 9, hp = idx & 511;
    int i = hp % 63, e = hp / 63;
    Wq[i * 6144 + inv_perm(hq) * 12 + e] = W2[idx];
  } else if (idx < R1e) {               // W1 scan
    int jj = idx - R0e;
    int hq = jj >> 6, i = jj & 63;
    Wq[i * 6144 + inv_perm(hq) * 12 + 9] = W1[jj];
  } else if (idx < R2e) {               // Wo scan
    int jj = idx - R1e;
    int o = jj >> 9, hp = jj & 511;
    int i = hp % 63, p = hp / 63;
    int j = o & 63, half = o >> 6;
    Woq[i * 1280 + j * 20 + half * 10 + p] = Wo[jj];
  } else if (idx < R3e) {               // Wc scan (pair-interleaved layout)
    int jj = idx - R2e;
    int hq = jj >> 8, cc = jj & 255;
    int p = inv_perm(hq);
    int slot = (p < 256) ? (2 * p) : (2 * (p - 256) + 1);
    WcpT[cc * 512 + slot] = Wc[jj];
  } else if (idx < R4e) {               // zero the 9th slots for 8-wide groups
    int z = idx - R3e;
    if (z < 28672) {                    // Wq[i][q][8], i = 8..63
      int i = 8 + (z >> 9), q = z & 511;
      Wq[i * 6144 + q * 12 + 8] = 0.f;
    } else {                            // Woq[i][j][8 or 18], i = 8..63
      int z2 = z - 28672;
      int i = 8 + (z2 >> 7), r = z2 & 127;
      int j = r & 63, half = r >> 6;
      Woq[i * 1280 + j * 20 + half * 10 + 8] = 0.f;
    }
  } else if (idx < R5e) {               // permuted biases
    int z = idx - R4e;
    if (z < 512) {
      int dq; int hq = perm_of(z, &dq);
      b1p[z] = b1[hq];
    } else {
      int q = z - 512;
      int dq; int hq = perm_of(q, &dq);
      b2p[q] = b2[hq];
    }
  }
}

// ---------------- main fused kernel ------------------------------------------
// 256 threads = 4 waves; wave rp owns rows 4rp..4rp+3; thread (rp,l) owns
// units q0=t, q1=t+256 and output cols (l, l+64) of its wave's 4 rows.
__global__ __launch_bounds__(256, 2)
void made_pk_kernel(
    const float* __restrict__ context, const float* __restrict__ WcpT,
    const float* __restrict__ b1p,
    const float* __restrict__ Wq, const float* __restrict__ Woq,
    const float* __restrict__ b2p, const float* __restrict__ bo,
    const float* __restrict__ eps, float* __restrict__ out) {
  __shared__ __align__(16) float ctxR[Rn][264];
  __shared__ __align__(16) float zpub[2][16];
  __shared__ __align__(16) float h1pub[2][9][16];
  __shared__ __align__(16) float h2pub[2][9][16];

  int t = threadIdx.x;
  int b0 = blockIdx.x * Rn;
  int rp = t >> 6, l = t & 63;
  int q0 = t, q1 = t + 256;

  int g0 = ((q0 < 72) ? q0 / 9 + 1 : (q0 - 72) / 8 + 9) - 1;
  int g1 = ((q1 - 72) / 8 + 9) - 1;
  int qm = t | 63;
  int gm0s = __builtin_amdgcn_readfirstlane(
      ((qm < 72) ? qm / 9 + 1 : (qm - 72) / 8 + 9) - 1);
  int gm1s = __builtin_amdgcn_readfirstlane(((qm + 256 - 72) / 8 + 9) - 1);

  // ---- stage ctx (16 rows) ----
  #pragma unroll
  for (int r = 0; r < Rn; ++r)
    ctxR[r][t] = context[(b0 + r) * CTXn + t];
  BARRIER();

  // ---- ctx GEMM, unit-pair packed (v16) ----
  f2 accu[16];
  {
    f2 bias = (f2){b1p[q0], b1p[q1]};
    #pragma unroll
    for (int r = 0; r < 16; ++r) accu[r] = bias;
  }
  {
    const float* wc = WcpT + 2 * t;
    #pragma clang loop unroll(disable)
    for (int c4 = 0; c4 < CTXn / 4; ++c4) {
      f2 wv0 = *(const f2*)&wc[0];
      f2 wv1 = *(const f2*)&wc[Hn];
      f2 wv2 = *(const f2*)&wc[2 * Hn];
      f2 wv3 = *(const f2*)&wc[3 * Hn];
      wc += 4 * Hn;
      #pragma unroll
      for (int hf = 0; hf < 2; ++hf) {
        float4 x[8];
        #pragma unroll
        for (int r = 0; r < 8; ++r) x[r] = *(const float4*)&ctxR[8 * hf + r][4 * c4];
        #pragma unroll
        for (int r = 0; r < 8; ++r) {
          accu[8 * hf + r] += (f2){x[r].x, x[r].x} * wv0;
          accu[8 * hf + r] += (f2){x[r].y, x[r].y} * wv1;
          accu[8 * hf + r] += (f2){x[r].z, x[r].z} * wv2;
          accu[8 * hf + r] += (f2){x[r].w, x[r].w} * wv3;
        }
      }
    }
  }
  f2 a10[8], a11[8], a20[8], a21[8];
  #pragma unroll
  for (int r2 = 0; r2 < 8; ++r2) {
    a10[r2] = (f2){accu[2 * r2].x, accu[2 * r2 + 1].x};
    a11[r2] = (f2){accu[2 * r2].y, accu[2 * r2 + 1].y};
  }
  {
    float bb0 = b2p[q0], bb1 = b2p[q1];
    #pragma unroll
    for (int r2 = 0; r2 < 8; ++r2) {
      a20[r2] = (f2){bb0, bb0};
      a21[r2] = (f2){bb1, bb1};
    }
  }
  f2 ocA[2], ocB[2];
  ocA[0] = ocA[1] = (f2){bo[l], bo[l]};
  ocB[0] = ocB[1] = (f2){bo[l + 64], bo[l + 64]};
  int r0 = b0 + 4 * rp;
  f2 ez01 = (f2){eps[(r0 + 0) * Dn + l], eps[(r0 + 1) * Dn + l]};
  f2 ez23 = (f2){eps[(r0 + 2) * Dn + l], eps[(r0 + 3) * Dn + l]};
  f2 zs01 = (f2){0.f, 0.f}, zs23 = zs01;
  f2 mus01 = zs01, mus23 = zs01, scs01 = zs01, scs23 = zs01;

  // current-step bulk weights (Wq[S-1]); rotated from prefetch each step
  float4 C1c0, C1c1, C1c2, C0c0, C0c1, C0c2;

  // ---- main loop: 2 barriers/step (+1 extra at S==7) ----
  #pragma clang loop unroll(disable)
  for (int S = 0; S < Dn; ++S) {
    // ======== phase 1: bulk (lagged) + E ========
    // prefetch Wq[S] -> P regs (feeds phase-2 finals AND next step's bulk)
    float4 P1c0, P1c1, P1c2, P0c0, P0c1, P0c2;
    bool pldB = (S <= gm1s);
    bool pldA = (S <= gm0s);
    if (pldB) {
      const float4* a4 = (const float4*)(Wq + (size_t)S * 6144 + (size_t)q1 * 12);
      P1c0 = a4[0]; P1c1 = a4[1]; P1c2 = a4[2];
      if (pldA) {
        const float4* b4 = (const float4*)(Wq + (size_t)S * 6144 + (size_t)q0 * 12);
        P0c0 = b4[0]; P0c1 = b4[1]; P0c2 = b4[2];
      }
    }

    if (S >= 1) {
      int i = S - 1, pb = i & 1;
      // D-accum: oc += Wo[i] . h2_{i}   (Woq row i, slot-8 zeroed for i>=8)
      const float4* w4 = (const float4*)(Woq + (size_t)i * 1280 + (size_t)l * 20);
      float4 B0 = w4[0], B1 = w4[1], B2_ = w4[2], B3 = w4[3], B4 = w4[4];
      float wBa[9] = {B0.x, B0.y, B0.z, B0.w, B1.x, B1.y, B1.z, B1.w, B2_.x};
      float wBb[9] = {B2_.z, B2_.w, B3.x, B3.y, B3.z, B3.w, B4.x, B4.y, B4.z};
      #pragma unroll
      for (int p = 0; p < 9; ++p) {
        float4 hq = *(const float4*)&h2pub[pb][p][4 * rp];
        f2 h01 = (f2){hq.x, hq.y}, h23 = (f2){hq.z, hq.w};
        f2 wa = (f2){wBa[p], wBa[p]}, wb = (f2){wBb[p], wBb[p]};
        ocA[0] += wa * h01; ocA[1] += wa * h23;
        ocB[0] += wb * h01; ocB[1] += wb * h23;
      }
    }

    // E: thread (rp, l==S): oc now complete through h2_{S-1} (own D-accum above)
    if (l == S) {
      f2 p01 = ocB[0], p23 = ocB[1];
      float s0 = fmaxf(p01.x, 0.f) + __logf(1.f + __expf(-fabsf(p01.x)));
      float s1 = fmaxf(p01.y, 0.f) + __logf(1.f + __expf(-fabsf(p01.y)));
      float s2 = fmaxf(p23.x, 0.f) + __logf(1.f + __expf(-fabsf(p23.x)));
      float s3 = fmaxf(p23.y, 0.f) + __logf(1.f + __expf(-fabsf(p23.y)));
      f2 sc01 = (f2){s0, s1}, sc23 = (f2){s2, s3};
      f2 z01 = ocA[0] + sc01 * ez01;
      f2 z23 = ocA[1] + sc23 * ez23;
      *(float4*)&zpub[S & 1][4 * rp] = (float4){z01.x, z01.y, z23.x, z23.y};
      zs01 = z01; zs23 = z23;
      mus01 = ocA[0]; mus23 = ocA[1];
      scs01 = sc01; scs23 = sc23;
    }

    if (S >= 1) {
      int i = S - 1, pb = i & 1;
      bool liveB = (i <= gm1s);
      bool liveA = (i <= gm0s);
      if (liveB) {
        // FA-accum: a1 += W1[i] * z_i
        float4 za = *(const float4*)&zpub[pb][0];
        float4 zb = *(const float4*)&zpub[pb][4];
        float4 zc = *(const float4*)&zpub[pb][8];
        float4 zd = *(const float4*)&zpub[pb][12];
        f2 zz[8] = {(f2){za.x, za.y}, (f2){za.z, za.w},
                    (f2){zb.x, zb.y}, (f2){zb.z, zb.w},
                    (f2){zc.x, zc.y}, (f2){zc.z, zc.w},
                    (f2){zd.x, zd.y}, (f2){zd.z, zd.w}};
        {
          f2 wv = (f2){C1c2.y, C1c2.y};
          #pragma unroll
          for (int r2 = 0; r2 < 8; ++r2) a11[r2] += wv * zz[r2];
        }
        if (liveA) {
          f2 wv = (f2){C0c2.y, C0c2.y};
          #pragma unroll
          for (int r2 = 0; r2 < 8; ++r2) a10[r2] += wv * zz[r2];
        }
        // MID-accum: a2 += W2[i, group-i cols] . h1_i  (slot-8 zeroed i>=8)
        float wA1[9] = {C1c0.x, C1c0.y, C1c0.z, C1c0.w,
                        C1c1.x, C1c1.y, C1c1.z, C1c1.w, C1c2.x};
        if (liveA) {
          float wA0[9] = {C0c0.x, C0c0.y, C0c0.z, C0c0.w,
                          C0c1.x, C0c1.y, C0c1.z, C0c1.w, C0c2.x};
          #pragma unroll
          for (int p = 0; p < 9; ++p) {
            float4 ha = *(const float4*)&h1pub[pb][p][0];
            float4 hb = *(const float4*)&h1pub[pb][p][4];
            float4 hc = *(const float4*)&h1pub[pb][p][8];
            float4 hd = *(const float4*)&h1pub[pb][p][12];
            f2 h[8] = {(f2){ha.x, ha.y}, (f2){ha.z, ha.w},
                       (f2){hb.x, hb.y}, (f2){hb.z, hb.w},
                       (f2){hc.x, hc.y}, (f2){hc.z, hc.w},
                       (f2){hd.x, hd.y}, (f2){hd.z, hd.w}};
            f2 wv1 = (f2){wA1[p], wA1[p]};
            f2 wv0 = (f2){wA0[p], wA0[p]};
            #pragma unroll
            for (int r2 = 0; r2 < 8; ++r2) {
              a21[r2] += wv1 * h[r2];
              a20[r2] += wv0 * h[r2];
            }
          }
        } else {
          #pragma unroll
          for (int p = 0; p < 9; ++p) {
            float4 ha = *(const float4*)&h1pub[pb][p][0];
            float4 hb = *(const float4*)&h1pub[pb][p][4];
            float4 hc = *(const float4*)&h1pub[pb][p][8];
            float4 hd = *(const float4*)&h1pub[pb][p][12];
            f2 h[8] = {(f2){ha.x, ha.y}, (f2){ha.z, ha.w},
                       (f2){hb.x, hb.y}, (f2){hb.z, hb.w},
                       (f2){hc.x, hc.y}, (f2){hc.z, hc.w},
                       (f2){hd.x, hd.y}, (f2){hd.z, hd.w}};
            f2 wv1 = (f2){wA1[p], wA1[p]};
            #pragma unroll
            for (int r2 = 0; r2 < 8; ++r2) a21[r2] += wv1 * h[r2];
          }
        }
      }
    }
    BARRIER();                                   // end phase 1: z_S visible

    // ======== phase 2: group-S finals, inline ========
    int ps = S & 1;
    int sb = (S < 8) ? 9 * S : 8 * S + 8;
    bool fin1 = (g1 == S);
    bool fin0 = (g0 == S);
    if (fin1) {
      float4 za = *(const float4*)&zpub[ps][0];
      float4 zb = *(const float4*)&zpub[ps][4];
      float4 zc = *(const float4*)&zpub[ps][8];
      float4 zd = *(const float4*)&zpub[ps][12];
      f2 zz[8] = {(f2){za.x, za.y}, (f2){za.z, za.w},
                  (f2){zb.x, zb.y}, (f2){zb.z, zb.w},
                  (f2){zc.x, zc.y}, (f2){zc.z, zc.w},
                  (f2){zd.x, zd.y}, (f2){zd.z, zd.w}};
      f2 wv = (f2){P1c2.y, P1c2.y};
      #pragma unroll
      for (int r2 = 0; r2 < 8; ++r2) a11[r2] += wv * zz[r2];
      int pp = q1 - sb;
      #pragma unroll
      for (int s = 0; s < 4; ++s) {
        *(float4*)&h1pub[ps][pp][4 * s] =
            (float4){fmaxf(a11[2 * s].x, 0.f), fmaxf(a11[2 * s].y, 0.f),
                     fmaxf(a11[2 * s + 1].x, 0.f), fmaxf(a11[2 * s + 1].y, 0.f)};
      }
    }
    if (fin0) {
      float4 za = *(const float4*)&zpub[ps][0];
      float4 zb = *(const float4*)&zpub[ps][4];
      float4 zc = *(const float4*)&zpub[ps][8];
      float4 zd = *(const float4*)&zpub[ps][12];
      f2 zz[8] = {(f2){za.x, za.y}, (f2){za.z, za.w},
                  (f2){zb.x, zb.y}, (f2){zb.z, zb.w},
                  (f2){zc.x, zc.y}, (f2){zc.z, zc.w},
                  (f2){zd.x, zd.y}, (f2){zd.z, zd.w}};
      f2 wv = (f2){P0c2.y, P0c2.y};
      #pragma unroll
      for (int r2 = 0; r2 < 8; ++r2) a10[r2] += wv * zz[r2];
      int pp = q0 - sb;
      #pragma unroll
      for (int s = 0; s < 4; ++s) {
        *(float4*)&h1pub[ps][pp][4 * s] =
            (float4){fmaxf(a10[2 * s].x, 0.f), fmaxf(a10[2 * s].y, 0.f),
                     fmaxf(a10[2 * s + 1].x, 0.f), fmaxf(a10[2 * s + 1].y, 0.f)};
      }
    }
    WAVE_LDS_FENCE();          // group units wave-contiguous (except S==7)
    if (S == 7) BARRIER();     // group 7 spans threads 63..71 (two waves)
    if (fin1) {
      float wc[9] = {P1c0.x, P1c0.y, P1c0.z, P1c0.w,
                     P1c1.x, P1c1.y, P1c1.z, P1c1.w, P1c2.x};
      #pragma unroll
      for (int k = 0; k < 9; ++k) {
        float4 ha = *(const float4*)&h1pub[ps][k][0];
        float4 hb = *(const float4*)&h1pub[ps][k][4];
        float4 hc = *(const float4*)&h1pub[ps][k][8];
        float4 hd = *(const float4*)&h1pub[ps][k][12];
        f2 h[8] = {(f2){ha.x, ha.y}, (f2){ha.z, ha.w},
                   (f2){hb.x, hb.y}, (f2){hb.z, hb.w},
                   (f2){hc.x, hc.y}, (f2){hc.z, hc.w},
                   (f2){hd.x, hd.y}, (f2){hd.z, hd.w}};
        f2 wv = (f2){wc[k], wc[k]};
        #pragma unroll
        for (int r2 = 0; r2 < 8; ++r2) a21[r2] += wv * h[r2];
      }
      int pp = q1 - sb;
      #pragma unroll
      for (int s = 0; s < 4; ++s) {
        *(float4*)&h2pub[ps][pp][4 * s] =
            (float4){fmaxf(a21[2 * s].x, 0.f), fmaxf(a21[2 * s].y, 0.f),
                     fmaxf(a21[2 * s + 1].x, 0.f), fmaxf(a21[2 * s + 1].y, 0.f)};
      }
    }
    if (fin0) {
      float wc[9] = {P0c0.x, P0c0.y, P0c0.z, P0c0.w,
                     P0c1.x, P0c1.y, P0c1.z, P0c1.w, P0c2.x};
      #pragma unroll
      for (int k = 0; k < 9; ++k) {
        float4 ha = *(const float4*)&h1pub[ps][k][0];
        float4 hb = *(const float4*)&h1pub[ps][k][4];
        float4 hc = *(const float4*)&h1pub[ps][k][8];
        float4 hd = *(const float4*)&h1pub[ps][k][12];
        f2 h[8] = {(f2){ha.x, ha.y}, (f2){ha.z, ha.w},
                   (f2){hb.x, hb.y}, (f2){hb.z, hb.w},
                   (f2){hc.x, hc.y}, (f2){hc.z, hc.w},
                   (f2){hd.x, hd.y}, (f2){hd.z, hd.w}};
        f2 wv = (f2){wc[k], wc[k]};
        #pragma unroll
        for (int r2 = 0; r2 < 8; ++r2) a20[r2] += wv * h[r2];
      }
      int pp = q0 - sb;
      #pragma unroll
      for (int s = 0; s < 4; ++s) {
        *(float4*)&h2pub[ps][pp][4 * s] =
            (float4){fmaxf(a20[2 * s].x, 0.f), fmaxf(a20[2 * s].y, 0.f),
                     fmaxf(a20[2 * s + 1].x, 0.f), fmaxf(a20[2 * s + 1].y, 0.f)};
      }
    }
    BARRIER();                                   // end phase 2: h1_S/h2_S visible

    // rotate prefetched Wq[S] into current regs (bulk of step S+1 uses i=S)
    if (pldB) {
      C1c0 = P1c0; C1c1 = P1c1; C1c2 = P1c2;
      if (pldA) { C0c0 = P0c0; C0c1 = P0c1; C0c2 = P0c2; }
    }
  }

  // ---- epilogue: thread (rp, l) holds z/mu/sc for rows 4rp..4rp+3, col l ----
  out[(r0 + 0) * Dn + l] = zs01.x;
  out[(r0 + 1) * Dn + l] = zs01.y;
  out[(r0 + 2) * Dn + l] = zs23.x;
  out[(r0 + 3) * Dn + l] = zs23.y;
  out[BD + (r0 + 0) * Dn + l] = mus01.x;
  out[BD + (r0 + 1) * Dn + l] = mus01.y;
  out[BD + (r0 + 2) * Dn + l] = mus23.x;
  out[BD + (r0 + 3) * Dn + l] = mus23.y;
  out[2 * BD + (r0 + 0) * Dn + l] = scs01.x;
  out[2 * BD + (r0 + 1) * Dn + l] = scs01.y;
  out[2 * BD + (r0 + 2) * Dn + l] = scs23.x;
  out[2 * BD + (r0 + 3) * Dn + l] = scs23.y;
}

extern "C" void kernel_launch(void* const* d_in, const int* in_sizes, int n_in,
                              void* d_out, int out_size, void* d_ws, size_t ws_size,
                              hipStream_t stream) {
  const float* context = (const float*)d_in[0];
  const float* eps     = (const float*)d_in[1];
  const float* W1      = (const float*)d_in[2];
  const float* b1      = (const float*)d_in[3];
  const float* Wc      = (const float*)d_in[4];
  const float* W2      = (const float*)d_in[5];
  const float* b2      = (const float*)d_in[6];
  const float* Wo      = (const float*)d_in[7];
  const float* bo      = (const float*)d_in[8];
  float* out = (float*)d_out;

  float* ws   = (float*)d_ws;
  float* Wq   = ws;                        // 393216 floats
  float* Woq  = Wq + WQ_SZ;                //  81920
  float* WcpT = Woq + WOQ_SZ;              // 131072
  float* b1p  = WcpT + WCP_SZ;             //    512
  float* b2p  = b1p + 512;                 //    512
  // total ws use: ~2.4 MB (L2-resident)

  prep_kernel<<<(R5e + 255) / 256, 256, 0, stream>>>(
      W1, Wc, W2, Wo, b1, b2, Wq, Woq, WcpT, b1p, b2p);
  made_pk_kernel<<<Bn / Rn, 256, 0, stream>>>(context, WcpT, b1p, Wq, Woq,
                                              b2p, bo, eps, out);
}